// Round 1
// 438.917 us; speedup vs baseline: 1.1037x; 1.1037x over previous
//
#include <hip/hip_runtime.h>

// masks [N=100, H=800, W=1280] fp32; out[n] = [xmin, ymin, xmax, ymax] as float.
//
// Single kernel, one block per mask, no workspace, no atomics.
// ymin is exact as soon as the first hit-bearing chunk from the top is found
// (all rows above it are hit-free); ymax symmetric from the bottom. For x we
// early-exit once xmin==0 && xmax==W-1. Uniform-random bench data resolves in
// phase 0 (top+bottom chunk, 160 KB/mask); worst case degrades to one full
// read of the mask (~4 MB/block) and stays correct.

#define N_MASKS 100
#define H 800
#define W 1280
#define F4_PER_ROW (W / 4)                    // 320
#define CH_ROWS 16
#define NCH (H / CH_ROWS)                     // 50 chunks
#define F4_PER_CHUNK (CH_ROWS * F4_PER_ROW)   // 5120
#define THREADS 1024
#define NWAVES (THREADS / 64)                 // 16

template <int NF4, int TH>
__device__ __forceinline__ bool scan_chunk(const float4* __restrict__ base, int rowBase, int tt,
                                           int& xmin, int& xmax, int& ymin, int& ymax) {
    bool hit = false;
#pragma unroll
    for (int k = 0; k < NF4; ++k) {
        int i = tt + k * TH;                  // coalesced float4 stream
        int row = i / F4_PER_ROW;
        int c4 = i - row * F4_PER_ROW;
        float4 v = base[i];
        unsigned m = (unsigned)(v.x > 0.5f)
                   | ((unsigned)(v.y > 0.5f) << 1)
                   | ((unsigned)(v.z > 0.5f) << 2)
                   | ((unsigned)(v.w > 0.5f) << 3);
        if (m) {
            int xb = c4 * 4;
            int y = rowBase + row;
            xmin = min(xmin, xb + (__ffs(m) - 1));
            xmax = max(xmax, xb + (31 - __clz(m)));
            ymin = min(ymin, y);
            ymax = max(ymax, y);
            hit = true;
        }
    }
    return hit;
}

// Block-wide reduce of the 4 accumulators into bbox[] = {xmin, ymin, xmax, ymax}.
// All threads see the result after return (uniform).
__device__ __forceinline__ void block_reduce_box(int t, int xmin, int xmax, int ymin, int ymax,
                                                 int (*red)[4], int* bbox) {
#pragma unroll
    for (int off = 32; off > 0; off >>= 1) {
        xmin = min(xmin, __shfl_down(xmin, off, 64));
        xmax = max(xmax, __shfl_down(xmax, off, 64));
        ymin = min(ymin, __shfl_down(ymin, off, 64));
        ymax = max(ymax, __shfl_down(ymax, off, 64));
    }
    __syncthreads();                          // protect red[] from previous round's readers
    if ((t & 63) == 0) {
        int w = t >> 6;
        red[w][0] = xmin; red[w][1] = xmax; red[w][2] = ymin; red[w][3] = ymax;
    }
    __syncthreads();
    if (t == 0) {
        int a = red[0][0], b = red[0][1], c = red[0][2], d = red[0][3];
#pragma unroll
        for (int w = 1; w < NWAVES; ++w) {
            a = min(a, red[w][0]); b = max(b, red[w][1]);
            c = min(c, red[w][2]); d = max(d, red[w][3]);
        }
        bbox[0] = a; bbox[1] = c; bbox[2] = b; bbox[3] = d;
    }
    __syncthreads();
}

__global__ __launch_bounds__(THREADS) void boxgen(const float4* __restrict__ masks,
                                                  float* __restrict__ out) {
    const int mask = blockIdx.x;
    const int t = threadIdx.x;
    const float4* mbase = masks + (size_t)mask * (H * F4_PER_ROW);

    __shared__ int red[NWAVES][4];
    __shared__ int bbox[4];

    int xmin = W, xmax = -1, ymin = H, ymax = -1;  // sentinels match jnp.where fallback

    // Phase 0: lower half-block scans top chunk, upper half scans bottom chunk.
    const int half = t >> 9;
    const int tt = t & 511;
    const int c0 = half ? (NCH - 1) : 0;
    bool h0 = scan_chunk<F4_PER_CHUNK / 512, 512>(mbase + (size_t)c0 * F4_PER_CHUNK,
                                                  c0 * CH_ROWS, tt, xmin, xmax, ymin, ymax);
    int topFound = __syncthreads_or((half == 0) && h0);
    int botFound = __syncthreads_or((half == 1) && h0);

    // Walk down from the top until the first hit-bearing chunk fixes ymin.
    int ct = 1, cb = NCH - 2;
    while (!topFound && ct <= cb) {
        bool h = scan_chunk<F4_PER_CHUNK / THREADS, THREADS>(
            mbase + (size_t)ct * F4_PER_CHUNK, ct * CH_ROWS, t, xmin, xmax, ymin, ymax);
        topFound = __syncthreads_or((int)h);
        ++ct;
    }
    // Walk up from the bottom until the first hit-bearing chunk fixes ymax.
    while (!botFound && cb >= ct) {
        bool h = scan_chunk<F4_PER_CHUNK / THREADS, THREADS>(
            mbase + (size_t)cb * F4_PER_CHUNK, cb * CH_ROWS, t, xmin, xmax, ymin, ymax);
        botFound = __syncthreads_or((int)h);
        --cb;
    }

    // Middle chunks only matter for xmin/xmax; stop once the x-range is saturated.
    block_reduce_box(t, xmin, xmax, ymin, ymax, red, bbox);
    for (int c = ct; c <= cb; ++c) {
        if (bbox[0] == 0 && bbox[2] == W - 1) break;   // uniform read, race-free
        scan_chunk<F4_PER_CHUNK / THREADS, THREADS>(
            mbase + (size_t)c * F4_PER_CHUNK, c * CH_ROWS, t, xmin, xmax, ymin, ymax);
        block_reduce_box(t, xmin, xmax, ymin, ymax, red, bbox);
    }

    if (t == 0) {
        float4 r;
        r.x = (float)bbox[0];   // xmin
        r.y = (float)bbox[1];   // ymin
        r.z = (float)bbox[2];   // xmax
        r.w = (float)bbox[3];   // ymax
        reinterpret_cast<float4*>(out)[mask] = r;
    }
}

extern "C" void kernel_launch(void* const* d_in, const int* in_sizes, int n_in,
                              void* d_out, int out_size, void* d_ws, size_t ws_size,
                              hipStream_t stream) {
    boxgen<<<dim3(N_MASKS), dim3(THREADS), 0, stream>>>((const float4*)d_in[0], (float*)d_out);
}